// Round 5
// baseline (235.078 us; speedup 1.0000x reference)
//
#include <hip/hip_runtime.h>
#include <hip/hip_bf16.h>

#define BB 64
#define PP 576
#define DD 1024
#define HH 512

typedef __attribute__((ext_vector_type(4))) float f32x4;
typedef __attribute__((ext_vector_type(8))) short bf16x8;

__device__ __forceinline__ unsigned short f2bf(float f) {
    union { float f; unsigned u; } v; v.f = f;
    unsigned r = v.u + 0x7FFF + ((v.u >> 16) & 1);
    return (unsigned short)(r >> 16);
}

__device__ __forceinline__ float fast_tanh(float x) {
    float e = __expf(2.f * x);
    return 1.f - 2.f / (e + 1.f);
}

__device__ __forceinline__ void gload16(const void* g, void* l) {
    __builtin_amdgcn_global_load_lds((const __attribute__((address_space(1))) unsigned int*)g,
                                     (__attribute__((address_space(3))) unsigned int*)l,
                                     16, 0, 0);
}

// pack 8 f32 -> bf16x8 via HW packed convert (RNE)
__device__ __forceinline__ bf16x8 cvt8(f32x4 a, f32x4 b) {
    union { bf16x8 v; unsigned u[4]; } r;
    asm("v_cvt_pk_bf16_f32 %0, %1, %2" : "=v"(r.u[0]) : "v"(a.x), "v"(a.y));
    asm("v_cvt_pk_bf16_f32 %0, %1, %2" : "=v"(r.u[1]) : "v"(a.z), "v"(a.w));
    asm("v_cvt_pk_bf16_f32 %0, %1, %2" : "=v"(r.u[2]) : "v"(b.x), "v"(b.y));
    asm("v_cvt_pk_bf16_f32 %0, %1, %2" : "=v"(r.u[3]) : "v"(b.z), "v"(b.w));
    return r.v;
}

// ---- kernel 0: convert W_img fp32 -> bf16 in ws ----
__global__ __launch_bounds__(256) void k_convert(const float* __restrict__ w,
                                                 unsigned short* __restrict__ o) {
    int i = (blockIdx.x * 256 + threadIdx.x) * 4;
    f32x4 v = *(const f32x4*)(w + i);
    ushort4 r;
    r.x = f2bf(v.x); r.y = f2bf(v.y); r.z = f2bf(v.z); r.w = f2bf(v.w);
    *(ushort4*)(o + i) = r;
}

// ---- kernel 1: g[b][h] = tanh(seq[b]·W_seq[h]) * W_w[h]  (fp32 exact path) ----
__global__ __launch_bounds__(128) void k_seq(const float* __restrict__ seq,
                                             const float* __restrict__ W_seq,
                                             const float* __restrict__ W_w,
                                             float* __restrict__ g) {
    int b = blockIdx.x;
    int h = blockIdx.y * 128 + threadIdx.x;
    __shared__ float s_seq[DD];
    #pragma unroll
    for (int i = 0; i < 8; i++) s_seq[threadIdx.x + i * 128] = seq[b * DD + threadIdx.x + i * 128];
    __syncthreads();
    const float* wr = W_seq + (size_t)h * DD;
    float acc = 0.f;
    #pragma unroll 4
    for (int d = 0; d < DD; d += 4) {
        f32x4 w4 = *(const f32x4*)(wr + d);
        acc += w4.x * s_seq[d] + w4.y * s_seq[d + 1] + w4.z * s_seq[d + 2] + w4.w * s_seq[d + 3];
    }
    g[b * HH + h] = fast_tanh(acc) * W_w[h];
}

// ---- kernel 2: partial scores — BARRIER-FREE per-wave pipeline ----
// Block 256 thr = 4 waves. Tile BM=64 x HC=256, BK=32, 32 rounds.
// A: loaded DIRECTLY global->VGPR in MFMA fragment layout (lane=row l&15,
//    k-chunk (l>>4)*8): 16 rows x 128B full cache lines per m-frag -> coalesced.
//    Converted in-reg via v_cvt_pk_bf16_f32. No A LDS, no block barrier.
// B: per-wave global_load_lds (wave stages exactly the rows it consumes),
//    double-buffered, pre-swizzled source (chunk ^ ((row>>1)&3)), exact vmcnt.
// 12 vmem ops per stage (8 A dwordx4 + 4 B gload16); in-order retirement ->
// vmcnt(12) at each compute retires precisely the current stage.
__global__ __launch_bounds__(256, 2) void k_scores(const float* __restrict__ img,
                                                   const unsigned short* __restrict__ Wb,
                                                   const float* __restrict__ g,
                                                   float* __restrict__ sp) {
    int b = blockIdx.y;
    int rt = blockIdx.x % 9;
    int ch = blockIdx.x / 9;
    int p0 = rt * 64;
    int h0 = ch * 256;
    int tid = threadIdx.x;
    int w = tid >> 6, lane = tid & 63;
    int r15 = lane & 15;
    int kq = lane >> 4;                      // 0..3: k-chunk selector
    int csw = kq ^ ((r15 >> 1) & 3);         // swizzled B chunk for ds_read

    __shared__ unsigned short Bs[2][256 * 32];   // 2 x 16 KB

    float gr[4];
    #pragma unroll
    for (int n = 0; n < 4; ++n) gr[n] = g[b * HH + h0 + w * 64 + n * 16 + r15];

    f32x4 acc[4][4];
    #pragma unroll
    for (int m = 0; m < 4; m++)
        #pragma unroll
        for (int n = 0; n < 4; n++) acc[m][n] = (f32x4)0.f;

    // A fragment base addresses (per m): row p0+m*16+r15, col kq*8
    const float* abase[4];
    #pragma unroll
    for (int m = 0; m < 4; ++m)
        abase[m] = img + ((size_t)(b * PP + p0 + m * 16 + r15)) * DD + kq * 8;

    // B staging geometry
    int rl = lane >> 2;
    int bswz = (lane & 3) ^ ((rl >> 1) & 3);
    const unsigned short* bbase = Wb + (size_t)h0 * DD;

    f32x4 uaE[4][2], uaO[4][2];   // A prefetch ring, static slots (even/odd)

    auto issueA = [&](f32x4 (&ua)[4][2], int kr) {
        int k0 = kr * 32;
        #pragma unroll
        for (int m = 0; m < 4; ++m) {
            ua[m][0] = *(const f32x4*)(abase[m] + k0);
            ua[m][1] = *(const f32x4*)(abase[m] + k0 + 4);
        }
    };
    auto issueB = [&](unsigned short* Bsb, int kr) {
        int k0 = kr * 32;
        #pragma unroll
        for (int i = 0; i < 4; ++i) {
            int hr = w * 64 + i * 16 + rl;
            gload16(bbase + (size_t)hr * DD + k0 + bswz * 8, Bsb + (w * 4 + i) * 512);
        }
    };
    auto compute = [&](const f32x4 (&ua)[4][2], const unsigned short* Bsb) {
        bf16x8 af[4], bf[4];
        #pragma unroll
        for (int m = 0; m < 4; ++m) af[m] = cvt8(ua[m][0], ua[m][1]);
        #pragma unroll
        for (int n = 0; n < 4; ++n)
            bf[n] = *(const bf16x8*)&Bsb[(w * 64 + n * 16 + r15) * 32 + csw * 8];
        #pragma unroll
        for (int m = 0; m < 4; ++m)
            #pragma unroll
            for (int n = 0; n < 4; ++n)
                acc[m][n] = __builtin_amdgcn_mfma_f32_16x16x32_bf16(af[m], bf[n], acc[m][n], 0, 0, 0);
    };

    // prologue: stage 0
    issueA(uaE, 0);
    issueB(&Bs[0][0], 0);

    for (int kr2 = 0; kr2 < 16; ++kr2) {
        int kr = kr2 * 2;
        // stage kr+1 -> odd slots
        issueA(uaO, kr + 1);
        issueB(&Bs[1][0], kr + 1);
        asm volatile("s_waitcnt vmcnt(12)" ::: "memory");   // stage kr landed
        __builtin_amdgcn_sched_barrier(0);
        compute(uaE, &Bs[0][0]);
        // stage kr+2 -> even slots
        if (kr2 < 15) {
            issueA(uaE, kr + 2);
            issueB(&Bs[0][0], kr + 2);
            asm volatile("s_waitcnt vmcnt(12)" ::: "memory");  // stage kr+1 landed
        } else {
            asm volatile("s_waitcnt vmcnt(0)" ::: "memory");
        }
        __builtin_amdgcn_sched_barrier(0);
        compute(uaO, &Bs[1][0]);
    }

    // epilogue: tanh * g, reduce over this block's 256 cols
    float part[4][4];
    #pragma unroll
    for (int m = 0; m < 4; m++)
        #pragma unroll
        for (int j = 0; j < 4; j++) part[m][j] = 0.f;
    #pragma unroll
    for (int m = 0; m < 4; ++m)
        #pragma unroll
        for (int n = 0; n < 4; ++n) {
            float gv = gr[n];
            f32x4 v = acc[m][n];
            #pragma unroll
            for (int j = 0; j < 4; ++j) part[m][j] += fast_tanh(v[j]) * gv;
        }
    #pragma unroll
    for (int mask = 1; mask < 16; mask <<= 1)
        #pragma unroll
        for (int m = 0; m < 4; ++m)
            #pragma unroll
            for (int j = 0; j < 4; ++j)
                part[m][j] += __shfl_xor(part[m][j], mask, 64);

    __syncthreads();                      // all waves done reading Bs
    float* red = (float*)&Bs[0][0];
    if (r15 == 0) {
        int hi = lane >> 4;
        #pragma unroll
        for (int m = 0; m < 4; ++m)
            #pragma unroll
            for (int j = 0; j < 4; ++j)
                red[w * 64 + m * 16 + hi * 4 + j] = part[m][j];
    }
    __syncthreads();
    if (tid < 64) {
        float s = red[tid] + red[64 + tid] + red[128 + tid] + red[192 + tid];
        sp[(size_t)ch * (BB * PP) + b * PP + p0 + tid] = s;
    }
}

// ---- kernel 3: sum the 2 col-half partials + softmax over P per batch ----
__global__ __launch_bounds__(576) void k_softmax(const float* __restrict__ sp,
                                                 float* __restrict__ alpha) {
    int b = blockIdx.x;
    int t = threadIdx.x;  // 0..575
    __shared__ float red[9];
    float s = sp[b * PP + t] + sp[BB * PP + b * PP + t];
    float m = s;
    #pragma unroll
    for (int off = 32; off; off >>= 1) m = fmaxf(m, __shfl_xor(m, off, 64));
    int w = t >> 6;
    if ((t & 63) == 0) red[w] = m;
    __syncthreads();
    float gm = red[0];
    #pragma unroll
    for (int i = 1; i < 9; i++) gm = fmaxf(gm, red[i]);
    float e = __expf(s - gm);
    float sum = e;
    #pragma unroll
    for (int off = 32; off; off >>= 1) sum += __shfl_xor(sum, off, 64);
    __syncthreads();
    if ((t & 63) == 0) red[w] = sum;
    __syncthreads();
    float gsum = 0.f;
    #pragma unroll
    for (int i = 0; i < 9; i++) gsum += red[i];
    alpha[b * PP + t] = e / gsum;
}

// ---- kernel 4: partial weighted sums over 64-patch chunks ----
__global__ __launch_bounds__(256) void k_attend(const float* __restrict__ img,
                                                const float* __restrict__ alpha,
                                                float* __restrict__ part) {
    int b = blockIdx.y;
    int pc = blockIdx.x;  // 0..8
    int t = threadIdx.x;
    __shared__ float al[64];
    if (t < 64) al[t] = alpha[b * PP + pc * 64 + t];
    __syncthreads();
    int d = t * 4;
    f32x4 acc = (f32x4)0.f;
    const float* base = img + ((size_t)b * PP + (size_t)pc * 64) * DD + d;
    #pragma unroll 4
    for (int i = 0; i < 64; i++) {
        f32x4 v = *(const f32x4*)(base + (size_t)i * DD);
        acc += al[i] * v;
    }
    float* o = part + ((size_t)pc * BB + b) * DD + d;
    *(f32x4*)o = acc;
}

// ---- kernel 5: reduce the 9 partials ----
__global__ __launch_bounds__(256) void k_reduce(const float* __restrict__ part,
                                                float* __restrict__ out) {
    int i = blockIdx.x * 256 + threadIdx.x;  // 0..65535
    float s = 0.f;
    #pragma unroll
    for (int pc = 0; pc < 9; pc++) s += part[pc * (BB * DD) + i];
    out[i] = s;
}

extern "C" void kernel_launch(void* const* d_in, const int* in_sizes, int n_in,
                              void* d_out, int out_size, void* d_ws, size_t ws_size,
                              hipStream_t stream) {
    const float* seq   = (const float*)d_in[0];   // [64,1024]
    const float* img   = (const float*)d_in[1];   // [64,576,1024]
    const float* W_seq = (const float*)d_in[2];   // [512,1024]
    const float* W_img = (const float*)d_in[3];   // [512,1024]
    const float* W_w   = (const float*)d_in[4];   // [1,512]
    float* out = (float*)d_out;                   // [64,1024]

    char* ws = (char*)d_ws;
    unsigned short* Wb = (unsigned short*)ws;                        // 1 MB
    float* g      = (float*)(ws + 1048576);                          // 128 KB
    float* sp     = (float*)(ws + 1048576 + 131072);                 // 2*144 KB (partial scores)
    float* alpha  = (float*)(ws + 1048576 + 131072 + 294912);        // 144 KB
    float* part   = (float*)(ws + 1048576 + 131072 + 294912 + 147456); // 2.25 MB

    k_convert<<<512, 256, 0, stream>>>(W_img, Wb);
    k_seq<<<dim3(BB, 4), 128, 0, stream>>>(seq, W_seq, W_w, g);
    k_scores<<<dim3(18, BB), 256, 0, stream>>>(img, Wb, g, sp);
    k_softmax<<<BB, 576, 0, stream>>>(sp, alpha);
    k_attend<<<dim3(9, BB), 256, 0, stream>>>(img, alpha, part);
    k_reduce<<<256, 256, 0, stream>>>(part, out);
}

// Round 6
// 227.843 us; speedup vs baseline: 1.0318x; 1.0318x over previous
//
#include <hip/hip_runtime.h>
#include <hip/hip_bf16.h>

#define BB 64
#define PP 576
#define DD 1024
#define HH 512

typedef __attribute__((ext_vector_type(4))) float f32x4;
typedef __attribute__((ext_vector_type(8))) short bf16x8;

__device__ __forceinline__ unsigned short f2bf(float f) {
    union { float f; unsigned u; } v; v.f = f;
    unsigned r = v.u + 0x7FFF + ((v.u >> 16) & 1);
    return (unsigned short)(r >> 16);
}

__device__ __forceinline__ float fast_tanh(float x) {
    float e = __expf(2.f * x);
    return 1.f - 2.f / (e + 1.f);
}

__device__ __forceinline__ void gload16(const void* g, void* l) {
    __builtin_amdgcn_global_load_lds((const __attribute__((address_space(1))) unsigned int*)g,
                                     (__attribute__((address_space(3))) unsigned int*)l,
                                     16, 0, 0);
}

// pack 8 f32 -> bf16x8 via HW packed convert (RNE)
__device__ __forceinline__ bf16x8 cvt8(f32x4 a, f32x4 b) {
    union { bf16x8 v; unsigned u[4]; } r;
    asm("v_cvt_pk_bf16_f32 %0, %1, %2" : "=v"(r.u[0]) : "v"(a.x), "v"(a.y));
    asm("v_cvt_pk_bf16_f32 %0, %1, %2" : "=v"(r.u[1]) : "v"(a.z), "v"(a.w));
    asm("v_cvt_pk_bf16_f32 %0, %1, %2" : "=v"(r.u[2]) : "v"(b.x), "v"(b.y));
    asm("v_cvt_pk_bf16_f32 %0, %1, %2" : "=v"(r.u[3]) : "v"(b.z), "v"(b.w));
    return r.v;
}

#define WAIT24 asm volatile("s_waitcnt vmcnt(24)" ::: "memory")
#define WAIT12 asm volatile("s_waitcnt vmcnt(12)" ::: "memory")
#define WAIT0  asm volatile("s_waitcnt vmcnt(0)" ::: "memory")

// ---- kernel 0: convert W_img fp32 -> bf16 in ws ----
__global__ __launch_bounds__(256) void k_convert(const float* __restrict__ w,
                                                 unsigned short* __restrict__ o) {
    int i = (blockIdx.x * 256 + threadIdx.x) * 4;
    f32x4 v = *(const f32x4*)(w + i);
    ushort4 r;
    r.x = f2bf(v.x); r.y = f2bf(v.y); r.z = f2bf(v.z); r.w = f2bf(v.w);
    *(ushort4*)(o + i) = r;
}

// ---- kernel 1: g[b][h] = tanh(seq[b]·W_seq[h]) * W_w[h]  (fp32 exact path) ----
__global__ __launch_bounds__(128) void k_seq(const float* __restrict__ seq,
                                             const float* __restrict__ W_seq,
                                             const float* __restrict__ W_w,
                                             float* __restrict__ g) {
    int b = blockIdx.x;
    int h = blockIdx.y * 128 + threadIdx.x;
    __shared__ float s_seq[DD];
    #pragma unroll
    for (int i = 0; i < 8; i++) s_seq[threadIdx.x + i * 128] = seq[b * DD + threadIdx.x + i * 128];
    __syncthreads();
    const float* wr = W_seq + (size_t)h * DD;
    float acc = 0.f;
    #pragma unroll 4
    for (int d = 0; d < DD; d += 4) {
        f32x4 w4 = *(const f32x4*)(wr + d);
        acc += w4.x * s_seq[d] + w4.y * s_seq[d + 1] + w4.z * s_seq[d + 2] + w4.w * s_seq[d + 3];
    }
    g[b * HH + h] = fast_tanh(acc) * W_w[h];
}

// ---- kernel 2: partial scores — barrier-free RING-3 pipeline ----
// Block 256 thr = 4 waves. Tile BM=64 x HC=256, BK=32, 32 stages.
// A: global->VGPR in MFMA fragment layout, 3 named slots (static ring).
// B: per-wave global_load_lds into 3-deep LDS ring (wave stages exactly the
//    rows it consumes -> no barrier; ring reuse race-free: ds_reads consumed
//    by MFMAs before the k+3 issue).
// Counted waits: before compute(k), issued = 4(g) + 12*(k+3); vmcnt(24)
// retires exactly gr + stages <= k. Issue-to-use slack = 3 compute phases.
// XCD swizzle: ch-pairs (same rt,b) land on the same XCD for L2 A-reuse.
__global__ __launch_bounds__(256, 2) void k_scores(const float* __restrict__ img,
                                                   const unsigned short* __restrict__ Wb,
                                                   const float* __restrict__ g,
                                                   float* __restrict__ sp) {
    // bijective XCD swizzle (1152 = 8 * 144)
    int orig = blockIdx.x + 18 * blockIdx.y;
    int logical = (orig & 7) * 144 + (orig >> 3);
    int ch = logical & 1;
    int rt = (logical >> 1) % 9;
    int b  = logical / 18;
    int p0 = rt * 64;
    int h0 = ch * 256;
    int tid = threadIdx.x;
    int w = tid >> 6, lane = tid & 63;
    int r15 = lane & 15;
    int kq = lane >> 4;                      // 0..3: k-chunk selector
    int csw = kq ^ ((r15 >> 1) & 3);         // swizzled B chunk for ds_read

    __shared__ unsigned short Bs[3][256 * 32];   // 3 x 16 KB ring

    float gr[4];
    #pragma unroll
    for (int n = 0; n < 4; ++n) gr[n] = g[b * HH + h0 + w * 64 + n * 16 + r15];

    f32x4 acc[4][4];
    #pragma unroll
    for (int m = 0; m < 4; m++)
        #pragma unroll
        for (int n = 0; n < 4; n++) acc[m][n] = (f32x4)0.f;

    // A fragment base addresses (per m): row p0+m*16+r15, col kq*8
    const float* abase[4];
    #pragma unroll
    for (int m = 0; m < 4; ++m)
        abase[m] = img + ((size_t)(b * PP + p0 + m * 16 + r15)) * DD + kq * 8;

    // B staging geometry
    int rl = lane >> 2;
    int bswz = (lane & 3) ^ ((rl >> 1) & 3);
    const unsigned short* bbase = Wb + (size_t)h0 * DD;

    f32x4 uaS0[4][2], uaS1[4][2], uaS2[4][2];   // static ring-3 A slots

    auto issueA = [&](f32x4 (&ua)[4][2], int kr) {
        int k0 = kr * 32;
        #pragma unroll
        for (int m = 0; m < 4; ++m) {
            ua[m][0] = *(const f32x4*)(abase[m] + k0);
            ua[m][1] = *(const f32x4*)(abase[m] + k0 + 4);
        }
    };
    auto issueB = [&](unsigned short* Bsb, int kr) {
        int k0 = kr * 32;
        #pragma unroll
        for (int i = 0; i < 4; ++i) {
            int hr = w * 64 + i * 16 + rl;
            gload16(bbase + (size_t)hr * DD + k0 + bswz * 8, Bsb + (w * 4 + i) * 512);
        }
    };
    auto compute = [&](const f32x4 (&ua)[4][2], const unsigned short* Bsb) {
        bf16x8 af[4], bf[4];
        #pragma unroll
        for (int n = 0; n < 4; ++n)
            bf[n] = *(const bf16x8*)&Bsb[(w * 64 + n * 16 + r15) * 32 + csw * 8];
        #pragma unroll
        for (int m = 0; m < 4; ++m) af[m] = cvt8(ua[m][0], ua[m][1]);
        #pragma unroll
        for (int m = 0; m < 4; ++m)
            #pragma unroll
            for (int n = 0; n < 4; ++n)
                acc[m][n] = __builtin_amdgcn_mfma_f32_16x16x32_bf16(af[m], bf[n], acc[m][n], 0, 0, 0);
    };

    // prologue: stages 0,1,2
    issueA(uaS0, 0); issueB(&Bs[0][0], 0);
    issueA(uaS1, 1); issueB(&Bs[1][0], 1);
    issueA(uaS2, 2); issueB(&Bs[2][0], 2);

    // main loop: computes 0..26, issues 3..29 (no guards needed)
    for (int i = 0; i < 9; ++i) {
        int kr = 3 * i;
        WAIT24; compute(uaS0, &Bs[0][0]); issueA(uaS0, kr + 3); issueB(&Bs[0][0], kr + 3);
        WAIT24; compute(uaS1, &Bs[1][0]); issueA(uaS1, kr + 4); issueB(&Bs[1][0], kr + 4);
        WAIT24; compute(uaS2, &Bs[2][0]); issueA(uaS2, kr + 5); issueB(&Bs[2][0], kr + 5);
    }
    // tail: computes 27..31, issues 30,31
    WAIT24; compute(uaS0, &Bs[0][0]); issueA(uaS0, 30); issueB(&Bs[0][0], 30);
    WAIT24; compute(uaS1, &Bs[1][0]); issueA(uaS1, 31); issueB(&Bs[1][0], 31);
    WAIT24; compute(uaS2, &Bs[2][0]);
    WAIT12; compute(uaS0, &Bs[0][0]);
    WAIT0;  compute(uaS1, &Bs[1][0]);

    // epilogue: tanh * g, reduce over this block's 256 cols
    float part[4][4];
    #pragma unroll
    for (int m = 0; m < 4; m++)
        #pragma unroll
        for (int j = 0; j < 4; j++) part[m][j] = 0.f;
    #pragma unroll
    for (int m = 0; m < 4; ++m)
        #pragma unroll
        for (int n = 0; n < 4; ++n) {
            float gv = gr[n];
            f32x4 v = acc[m][n];
            #pragma unroll
            for (int j = 0; j < 4; ++j) part[m][j] += fast_tanh(v[j]) * gv;
        }
    #pragma unroll
    for (int mask = 1; mask < 16; mask <<= 1)
        #pragma unroll
        for (int m = 0; m < 4; ++m)
            #pragma unroll
            for (int j = 0; j < 4; ++j)
                part[m][j] += __shfl_xor(part[m][j], mask, 64);

    __syncthreads();                      // all waves done reading Bs
    float* red = (float*)&Bs[0][0];
    if (r15 == 0) {
        int hi = lane >> 4;
        #pragma unroll
        for (int m = 0; m < 4; ++m)
            #pragma unroll
            for (int j = 0; j < 4; ++j)
                red[w * 64 + m * 16 + hi * 4 + j] = part[m][j];
    }
    __syncthreads();
    if (tid < 64) {
        float s = red[tid] + red[64 + tid] + red[128 + tid] + red[192 + tid];
        sp[(size_t)ch * (BB * PP) + b * PP + p0 + tid] = s;
    }
}

// ---- kernel 3: sum the 2 col-half partials + softmax over P per batch ----
__global__ __launch_bounds__(576) void k_softmax(const float* __restrict__ sp,
                                                 float* __restrict__ alpha) {
    int b = blockIdx.x;
    int t = threadIdx.x;  // 0..575
    __shared__ float red[9];
    float s = sp[b * PP + t] + sp[BB * PP + b * PP + t];
    float m = s;
    #pragma unroll
    for (int off = 32; off; off >>= 1) m = fmaxf(m, __shfl_xor(m, off, 64));
    int w = t >> 6;
    if ((t & 63) == 0) red[w] = m;
    __syncthreads();
    float gm = red[0];
    #pragma unroll
    for (int i = 1; i < 9; i++) gm = fmaxf(gm, red[i]);
    float e = __expf(s - gm);
    float sum = e;
    #pragma unroll
    for (int off = 32; off; off >>= 1) sum += __shfl_xor(sum, off, 64);
    __syncthreads();
    if ((t & 63) == 0) red[w] = sum;
    __syncthreads();
    float gsum = 0.f;
    #pragma unroll
    for (int i = 0; i < 9; i++) gsum += red[i];
    alpha[b * PP + t] = e / gsum;
}

// ---- kernel 4: partial weighted sums over 64-patch chunks ----
__global__ __launch_bounds__(256) void k_attend(const float* __restrict__ img,
                                                const float* __restrict__ alpha,
                                                float* __restrict__ part) {
    int b = blockIdx.y;
    int pc = blockIdx.x;  // 0..8
    int t = threadIdx.x;
    __shared__ float al[64];
    if (t < 64) al[t] = alpha[b * PP + pc * 64 + t];
    __syncthreads();
    int d = t * 4;
    f32x4 acc = (f32x4)0.f;
    const float* base = img + ((size_t)b * PP + (size_t)pc * 64) * DD + d;
    #pragma unroll 4
    for (int i = 0; i < 64; i++) {
        f32x4 v = *(const f32x4*)(base + (size_t)i * DD);
        acc += al[i] * v;
    }
    float* o = part + ((size_t)pc * BB + b) * DD + d;
    *(f32x4*)o = acc;
}

// ---- kernel 5: reduce the 9 partials ----
__global__ __launch_bounds__(256) void k_reduce(const float* __restrict__ part,
                                                float* __restrict__ out) {
    int i = blockIdx.x * 256 + threadIdx.x;  // 0..65535
    float s = 0.f;
    #pragma unroll
    for (int pc = 0; pc < 9; pc++) s += part[pc * (BB * DD) + i];
    out[i] = s;
}

extern "C" void kernel_launch(void* const* d_in, const int* in_sizes, int n_in,
                              void* d_out, int out_size, void* d_ws, size_t ws_size,
                              hipStream_t stream) {
    const float* seq   = (const float*)d_in[0];   // [64,1024]
    const float* img   = (const float*)d_in[1];   // [64,576,1024]
    const float* W_seq = (const float*)d_in[2];   // [512,1024]
    const float* W_img = (const float*)d_in[3];   // [512,1024]
    const float* W_w   = (const float*)d_in[4];   // [1,512]
    float* out = (float*)d_out;                   // [64,1024]

    char* ws = (char*)d_ws;
    unsigned short* Wb = (unsigned short*)ws;                        // 1 MB
    float* g      = (float*)(ws + 1048576);                          // 128 KB
    float* sp     = (float*)(ws + 1048576 + 131072);                 // 2*144 KB (partial scores)
    float* alpha  = (float*)(ws + 1048576 + 131072 + 294912);        // 144 KB
    float* part   = (float*)(ws + 1048576 + 131072 + 294912 + 147456); // 2.25 MB

    k_convert<<<512, 256, 0, stream>>>(W_img, Wb);
    k_seq<<<dim3(BB, 4), 128, 0, stream>>>(seq, W_seq, W_w, g);
    k_scores<<<dim3(18, BB), 256, 0, stream>>>(img, Wb, g, sp);
    k_softmax<<<BB, 576, 0, stream>>>(sp, alpha);
    k_attend<<<dim3(9, BB), 256, 0, stream>>>(img, alpha, part);
    k_reduce<<<256, 256, 0, stream>>>(part, out);
}

// Round 7
// 135.155 us; speedup vs baseline: 1.7393x; 1.6858x over previous
//
#include <hip/hip_runtime.h>
#include <hip/hip_bf16.h>

#define BB 64
#define PP 576
#define DD 1024
#define HH 512

typedef __attribute__((ext_vector_type(4))) float f32x4;
typedef __attribute__((ext_vector_type(8))) short bf16x8;

__device__ __forceinline__ unsigned short f2bf(float f) {
    union { float f; unsigned u; } v; v.f = f;
    unsigned r = v.u + 0x7FFF + ((v.u >> 16) & 1);
    return (unsigned short)(r >> 16);
}

__device__ __forceinline__ float fast_tanh(float x) {
    float e = __expf(2.f * x);
    return 1.f - 2.f / (e + 1.f);
}

__device__ __forceinline__ void gload16(const void* g, void* l) {
    __builtin_amdgcn_global_load_lds((const __attribute__((address_space(1))) unsigned int*)g,
                                     (__attribute__((address_space(3))) unsigned int*)l,
                                     16, 0, 0);
}

// ---- kernel 0: convert W_img fp32 -> bf16 in ws ----
__global__ __launch_bounds__(256) void k_convert(const float* __restrict__ w,
                                                 unsigned short* __restrict__ o) {
    int i = (blockIdx.x * 256 + threadIdx.x) * 4;
    f32x4 v = *(const f32x4*)(w + i);
    ushort4 r;
    r.x = f2bf(v.x); r.y = f2bf(v.y); r.z = f2bf(v.z); r.w = f2bf(v.w);
    *(ushort4*)(o + i) = r;
}

// ---- kernel 1: g[b][h] = tanh(seq[b]·W_seq[h]) * W_w[h]  (fp32 exact path) ----
__global__ __launch_bounds__(128) void k_seq(const float* __restrict__ seq,
                                             const float* __restrict__ W_seq,
                                             const float* __restrict__ W_w,
                                             float* __restrict__ g) {
    int b = blockIdx.x;
    int h = blockIdx.y * 128 + threadIdx.x;
    __shared__ float s_seq[DD];
    #pragma unroll
    for (int i = 0; i < 8; i++) s_seq[threadIdx.x + i * 128] = seq[b * DD + threadIdx.x + i * 128];
    __syncthreads();
    const float* wr = W_seq + (size_t)h * DD;
    float acc = 0.f;
    #pragma unroll 4
    for (int d = 0; d < DD; d += 4) {
        f32x4 w4 = *(const f32x4*)(wr + d);
        acc += w4.x * s_seq[d] + w4.y * s_seq[d + 1] + w4.z * s_seq[d + 2] + w4.w * s_seq[d + 3];
    }
    g[b * HH + h] = fast_tanh(acc) * W_w[h];
}

// ---- kernel 2: partial scores via bf16 MFMA, round-2 structure, 4 blocks/CU ----
// Block: 256 thr = 4 waves. Tile BM=64 x HC=256, BK=64, 16 rounds, single-buffered.
// LDS = As 8KB + Bs 32KB = 40960 B exactly -> 4 blocks/CU (16 waves/CU).
// Latency hiding = inter-block wave overlap (m114), NOT intra-wave pipelining
// (rounds 3-6 all proved that path regresses here).
// LDS rows of 64 bf16 (128B), 16B-chunk XOR-swizzled: chunk_sw = chunk ^ (row&7).
__global__ __launch_bounds__(256, 4) void k_scores(const float* __restrict__ img,
                                                   const unsigned short* __restrict__ Wb,
                                                   const float* __restrict__ g,
                                                   float* __restrict__ sp) {
    int b = blockIdx.y;
    int rt = blockIdx.x % 9;
    int ch = blockIdx.x / 9;
    int p0 = rt * 64;
    int h0 = ch * 256;
    int tid = threadIdx.x;
    int w = tid >> 6, lane = tid & 63;

    __shared__ unsigned short As[64 * 64];    // 8 KB
    __shared__ unsigned short Bs[256 * 64];   // 32 KB  -> 40 KB total, 4 blocks/CU

    // g values for this thread's 4 col-frags, in registers
    float gr[4];
    #pragma unroll
    for (int n = 0; n < 4; ++n) gr[n] = g[b * HH + h0 + w * 64 + n * 16 + (lane & 15)];

    f32x4 acc[4][4];
    #pragma unroll
    for (int m = 0; m < 4; m++)
        #pragma unroll
        for (int n = 0; n < 4; n++) acc[m][n] = (f32x4)0.f;

    // A staging geometry: thread t handles row t>>2, cols (t&3)*16 .. +15
    int ar = tid >> 2;
    const float* asrc = img + ((size_t)(b * PP + p0 + ar)) * DD + (tid & 3) * 16;
    int cp = (tid & 3) * 2;
    int aw0 = ar * 64 + ((cp ^ (ar & 7)) * 8);
    int aw1 = ar * 64 + (((cp + 1) ^ (ar & 7)) * 8);

    // B staging geometry (global_load_lds, pre-swizzled source)
    int brow_l = lane >> 3;   // 0..7 within 8-row segment
    int bchunk = lane & 7;    // 16B chunk within 128B row

    for (int kr = 0; kr < 16; ++kr) {
        int k0 = kr * 64;
        if (kr) __syncthreads();
        // B: 8 wave-issues x 1KB, linear LDS dest, swizzled global source
        #pragma unroll
        for (int i = 0; i < 8; ++i) {
            int hr = (w * 8 + i) * 8 + brow_l;
            const unsigned short* src = Wb + (size_t)(h0 + hr) * DD + k0 + ((bchunk ^ (hr & 7)) * 8);
            gload16(src, &Bs[(w * 8 + i) * 512]);
        }
        // A: reg-stage 16 f32 -> bf16 -> 2 swizzled LDS writes
        f32x4 v0 = *(const f32x4*)(asrc + k0);
        f32x4 v1 = *(const f32x4*)(asrc + k0 + 4);
        f32x4 v2 = *(const f32x4*)(asrc + k0 + 8);
        f32x4 v3 = *(const f32x4*)(asrc + k0 + 12);
        bf16x8 pa, pb;
        pa[0] = (short)f2bf(v0.x); pa[1] = (short)f2bf(v0.y);
        pa[2] = (short)f2bf(v0.z); pa[3] = (short)f2bf(v0.w);
        pa[4] = (short)f2bf(v1.x); pa[5] = (short)f2bf(v1.y);
        pa[6] = (short)f2bf(v1.z); pa[7] = (short)f2bf(v1.w);
        pb[0] = (short)f2bf(v2.x); pb[1] = (short)f2bf(v2.y);
        pb[2] = (short)f2bf(v2.z); pb[3] = (short)f2bf(v2.w);
        pb[4] = (short)f2bf(v3.x); pb[5] = (short)f2bf(v3.y);
        pb[6] = (short)f2bf(v3.z); pb[7] = (short)f2bf(v3.w);
        *(bf16x8*)&As[aw0] = pa;
        *(bf16x8*)&As[aw1] = pb;
        __syncthreads();   // drains vmcnt (global_load_lds) + lgkm (ds_write)

        #pragma unroll
        for (int ks = 0; ks < 2; ++ks) {
            int cbase = ks * 4 + (lane >> 4);   // 16B chunk index 0..7
            bf16x8 af[4], bfv[4];
            #pragma unroll
            for (int m = 0; m < 4; ++m) {
                int row = m * 16 + (lane & 15);
                af[m] = *(const bf16x8*)&As[row * 64 + ((cbase ^ (row & 7)) * 8)];
            }
            #pragma unroll
            for (int n = 0; n < 4; ++n) {
                int hr = w * 64 + n * 16 + (lane & 15);
                bfv[n] = *(const bf16x8*)&Bs[hr * 64 + ((cbase ^ (hr & 7)) * 8)];
            }
            #pragma unroll
            for (int m = 0; m < 4; ++m)
                #pragma unroll
                for (int n = 0; n < 4; ++n)
                    acc[m][n] = __builtin_amdgcn_mfma_f32_16x16x32_bf16(af[m], bfv[n], acc[m][n], 0, 0, 0);
        }
    }

    // epilogue: tanh * g, reduce over this block's 256 cols
    float part[4][4];
    #pragma unroll
    for (int m = 0; m < 4; m++)
        #pragma unroll
        for (int j = 0; j < 4; j++) part[m][j] = 0.f;
    #pragma unroll
    for (int m = 0; m < 4; ++m)
        #pragma unroll
        for (int n = 0; n < 4; ++n) {
            float gv = gr[n];
            f32x4 v = acc[m][n];
            #pragma unroll
            for (int j = 0; j < 4; ++j) part[m][j] += fast_tanh(v[j]) * gv;
        }
    #pragma unroll
    for (int mask = 1; mask < 16; mask <<= 1)
        #pragma unroll
        for (int m = 0; m < 4; ++m)
            #pragma unroll
            for (int j = 0; j < 4; ++j)
                part[m][j] += __shfl_xor(part[m][j], mask, 64);

    __syncthreads();                 // all waves done reading As/Bs
    float* red = (float*)As;         // alias 1KB scratch onto As
    if ((lane & 15) == 0) {
        int hi = lane >> 4;
        #pragma unroll
        for (int m = 0; m < 4; ++m)
            #pragma unroll
            for (int j = 0; j < 4; ++j)
                red[w * 64 + m * 16 + hi * 4 + j] = part[m][j];
    }
    __syncthreads();
    if (tid < 64) {
        float s = red[tid] + red[64 + tid] + red[128 + tid] + red[192 + tid];
        sp[(size_t)ch * (BB * PP) + b * PP + p0 + tid] = s;
    }
}

// ---- kernel 3: sum the 2 col-half partials + softmax over P per batch ----
__global__ __launch_bounds__(576) void k_softmax(const float* __restrict__ sp,
                                                 float* __restrict__ alpha) {
    int b = blockIdx.x;
    int t = threadIdx.x;  // 0..575
    __shared__ float red[9];
    float s = sp[b * PP + t] + sp[BB * PP + b * PP + t];
    float m = s;
    #pragma unroll
    for (int off = 32; off; off >>= 1) m = fmaxf(m, __shfl_xor(m, off, 64));
    int w = t >> 6;
    if ((t & 63) == 0) red[w] = m;
    __syncthreads();
    float gm = red[0];
    #pragma unroll
    for (int i = 1; i < 9; i++) gm = fmaxf(gm, red[i]);
    float e = __expf(s - gm);
    float sum = e;
    #pragma unroll
    for (int off = 32; off; off >>= 1) sum += __shfl_xor(sum, off, 64);
    __syncthreads();
    if ((t & 63) == 0) red[w] = sum;
    __syncthreads();
    float gsum = 0.f;
    #pragma unroll
    for (int i = 0; i < 9; i++) gsum += red[i];
    alpha[b * PP + t] = e / gsum;
}

// ---- kernel 4: partial weighted sums over 64-patch chunks ----
__global__ __launch_bounds__(256) void k_attend(const float* __restrict__ img,
                                                const float* __restrict__ alpha,
                                                float* __restrict__ part) {
    int b = blockIdx.y;
    int pc = blockIdx.x;  // 0..8
    int t = threadIdx.x;
    __shared__ float al[64];
    if (t < 64) al[t] = alpha[b * PP + pc * 64 + t];
    __syncthreads();
    int d = t * 4;
    f32x4 acc = (f32x4)0.f;
    const float* base = img + ((size_t)b * PP + (size_t)pc * 64) * DD + d;
    #pragma unroll 4
    for (int i = 0; i < 64; i++) {
        f32x4 v = *(const f32x4*)(base + (size_t)i * DD);
        acc += al[i] * v;
    }
    float* o = part + ((size_t)pc * BB + b) * DD + d;
    *(f32x4*)o = acc;
}

// ---- kernel 5: reduce the 9 partials ----
__global__ __launch_bounds__(256) void k_reduce(const float* __restrict__ part,
                                                float* __restrict__ out) {
    int i = blockIdx.x * 256 + threadIdx.x;  // 0..65535
    float s = 0.f;
    #pragma unroll
    for (int pc = 0; pc < 9; pc++) s += part[pc * (BB * DD) + i];
    out[i] = s;
}

extern "C" void kernel_launch(void* const* d_in, const int* in_sizes, int n_in,
                              void* d_out, int out_size, void* d_ws, size_t ws_size,
                              hipStream_t stream) {
    const float* seq   = (const float*)d_in[0];   // [64,1024]
    const float* img   = (const float*)d_in[1];   // [64,576,1024]
    const float* W_seq = (const float*)d_in[2];   // [512,1024]
    const float* W_img = (const float*)d_in[3];   // [512,1024]
    const float* W_w   = (const float*)d_in[4];   // [1,512]
    float* out = (float*)d_out;                   // [64,1024]

    char* ws = (char*)d_ws;
    unsigned short* Wb = (unsigned short*)ws;                        // 1 MB
    float* g      = (float*)(ws + 1048576);                          // 128 KB
    float* sp     = (float*)(ws + 1048576 + 131072);                 // 2*144 KB (partial scores)
    float* alpha  = (float*)(ws + 1048576 + 131072 + 294912);        // 144 KB
    float* part   = (float*)(ws + 1048576 + 131072 + 294912 + 147456); // 2.25 MB

    k_convert<<<512, 256, 0, stream>>>(W_img, Wb);
    k_seq<<<dim3(BB, 4), 128, 0, stream>>>(seq, W_seq, W_w, g);
    k_scores<<<dim3(18, BB), 256, 0, stream>>>(img, Wb, g, sp);
    k_softmax<<<BB, 576, 0, stream>>>(sp, alpha);
    k_attend<<<dim3(9, BB), 256, 0, stream>>>(img, alpha, part);
    k_reduce<<<256, 256, 0, stream>>>(part, out);
}